// Round 9
// baseline (57.133 us; speedup 1.0000x reference)
//
#include <hip/hip_runtime.h>

// SoftDiceLoss: predictions [B=8, C=16, H=512, W=512] fp32, targets [B,H,W] int32.
// out[b] = -(1/C) * sum_c (2*overlap[b,c] + 1) / (i_sum[b,c] + count[b,c] + 1)
//
// Stage 1: 512 blocks = (8 batches x 64 slabs of 4096 positions) x 256 thr.
//   Each thread owns 16 positions; targets packed 4 bits each into ONE u64
//   (tpack). The 16 pred class-segments stream sequentially as 4-deep
//   float4 bursts with an explicit ONE-CLASS-AHEAD prefetch double buffer;
//   the in-loop body is load+accumulate only (isum[16]/ov[16]/cnt[16]
//   per-thread regs, statically indexed). ALL wave reductions (48 DPP
//   chains, pure VALU) run once after the loop -> LDS -> partial[comp][blk].
// Stage 2: 8 blocks x 64 threads: thread t reduces one slab-column,
//   lane 63 computes the 16 fracs and writes out[b].

constexpr int  C_CLS   = 16;
constexpr long HW      = 512L * 512L;   // 262144 positions per (b,c) plane
constexpr int  BATCH   = 8;
constexpr int  SLAB    = 4096;          // positions per block
constexpr int  SLABS   = (int)(HW / SLAB);   // 64 per batch
constexpr int  NBLK    = BATCH * SLABS;      // 512
constexpr int  NPART   = 3 * C_CLS;          // 48 components

// Full wave64 sum via DPP (rocPRIM pattern). Result valid in lane 63.
__device__ __forceinline__ float wave_reduce_dpp(float x) {
    int t;
    t = __builtin_amdgcn_update_dpp(0, __float_as_int(x), 0x111, 0xf, 0xf, true); // row_shr:1
    x += __int_as_float(t);
    t = __builtin_amdgcn_update_dpp(0, __float_as_int(x), 0x112, 0xf, 0xf, true); // row_shr:2
    x += __int_as_float(t);
    t = __builtin_amdgcn_update_dpp(0, __float_as_int(x), 0x114, 0xf, 0xf, true); // row_shr:4
    x += __int_as_float(t);
    t = __builtin_amdgcn_update_dpp(0, __float_as_int(x), 0x118, 0xf, 0xf, true); // row_shr:8
    x += __int_as_float(t);
    t = __builtin_amdgcn_update_dpp(0, __float_as_int(x), 0x142, 0xa, 0xf, true); // row_bcast:15
    x += __int_as_float(t);
    t = __builtin_amdgcn_update_dpp(0, __float_as_int(x), 0x143, 0xc, 0xf, true); // row_bcast:31
    x += __int_as_float(t);
    return x;
}

__global__ __launch_bounds__(256, 4)
void dice_partial_kernel(const float* __restrict__ pred,
                         const int*   __restrict__ tgt,
                         float*       __restrict__ partial) {
    const int g    = blockIdx.x;
    const int slab = g & (SLABS - 1);
    const int b    = g >> 6;
    const int tid  = threadIdx.x;
    const int lane = tid & 63;
    const int wv   = tid >> 6;

    const long sbase = (long)slab * SLAB;        // within plane
    const int* tb = tgt + (long)b * HW + sbase;

    // pack this thread's 16 target values into one u64 (4 bits each)
    unsigned long long tpack = 0ull;
#pragma unroll
    for (int j = 0; j < 4; ++j) {
        const int4 tv = *reinterpret_cast<const int4*>(tb + j * 1024 + tid * 4);
        const unsigned nib = (unsigned)tv.x | ((unsigned)tv.y << 4)
                           | ((unsigned)tv.z << 8) | ((unsigned)tv.w << 12);
        tpack |= (unsigned long long)nib << (16 * j);
    }

    const float* pb = pred + (long)b * C_CLS * HW + sbase + tid * 4;

    float isum[C_CLS], ov[C_CLS], cnt[C_CLS];

    // prefetch class 0 burst
    float4 pA0 = *reinterpret_cast<const float4*>(pb + 0 * 1024);
    float4 pA1 = *reinterpret_cast<const float4*>(pb + 1 * 1024);
    float4 pA2 = *reinterpret_cast<const float4*>(pb + 2 * 1024);
    float4 pA3 = *reinterpret_cast<const float4*>(pb + 3 * 1024);

#pragma unroll
    for (int c = 0; c < C_CLS; ++c) {
        // issue next class's burst before consuming current
        float4 pB0, pB1, pB2, pB3;
        if (c < C_CLS - 1) {
            const float* nb = pb + (long)(c + 1) * HW;
            pB0 = *reinterpret_cast<const float4*>(nb + 0 * 1024);
            pB1 = *reinterpret_cast<const float4*>(nb + 1 * 1024);
            pB2 = *reinterpret_cast<const float4*>(nb + 2 * 1024);
            pB3 = *reinterpret_cast<const float4*>(nb + 3 * 1024);
        }

        // exact per-nibble (t==c) mask: bit 4i of m = match at position i
        unsigned long long x = tpack ^ ((unsigned long long)c * 0x1111111111111111ull);
        x |= x >> 2;
        x |= x >> 1;
        const unsigned long long m = ~x & 0x1111111111111111ull;

        float is = 0.f, o = 0.f;
        {
            const unsigned mb0 = (unsigned)m;
            is += (pA0.x + pA0.y) + (pA0.z + pA0.w);
            o  += ((mb0 & 0x0001u) ? pA0.x : 0.f) + ((mb0 & 0x0010u) ? pA0.y : 0.f)
                + ((mb0 & 0x0100u) ? pA0.z : 0.f) + ((mb0 & 0x1000u) ? pA0.w : 0.f);
            const unsigned mb1 = (unsigned)(m >> 16);
            is += (pA1.x + pA1.y) + (pA1.z + pA1.w);
            o  += ((mb1 & 0x0001u) ? pA1.x : 0.f) + ((mb1 & 0x0010u) ? pA1.y : 0.f)
                + ((mb1 & 0x0100u) ? pA1.z : 0.f) + ((mb1 & 0x1000u) ? pA1.w : 0.f);
            const unsigned mb2 = (unsigned)(m >> 32);
            is += (pA2.x + pA2.y) + (pA2.z + pA2.w);
            o  += ((mb2 & 0x0001u) ? pA2.x : 0.f) + ((mb2 & 0x0010u) ? pA2.y : 0.f)
                + ((mb2 & 0x0100u) ? pA2.z : 0.f) + ((mb2 & 0x1000u) ? pA2.w : 0.f);
            const unsigned mb3 = (unsigned)(m >> 48);
            is += (pA3.x + pA3.y) + (pA3.z + pA3.w);
            o  += ((mb3 & 0x0001u) ? pA3.x : 0.f) + ((mb3 & 0x0010u) ? pA3.y : 0.f)
                + ((mb3 & 0x0100u) ? pA3.z : 0.f) + ((mb3 & 0x1000u) ? pA3.w : 0.f);
        }
        isum[c] = is;
        ov[c]   = o;
        cnt[c]  = (float)__popcll(m);

        pA0 = pB0; pA1 = pB1; pA2 = pB2; pA3 = pB3;
    }

    // 48 independent DPP wave reductions (pipelined, pure VALU)
    __shared__ float sm[4][NPART];
#pragma unroll
    for (int c = 0; c < C_CLS; ++c) {
        const float is = wave_reduce_dpp(isum[c]);
        const float o  = wave_reduce_dpp(ov[c]);
        const float cn = wave_reduce_dpp(cnt[c]);
        if (lane == 63) {
            sm[wv][c * 3 + 0] = is;
            sm[wv][c * 3 + 1] = o;
            sm[wv][c * 3 + 2] = cn;
        }
    }

    __syncthreads();
    if (tid < NPART) {
        // component-major layout: partial[comp][block] for coalesced stage-2
        partial[(long)tid * NBLK + g] =
            (sm[0][tid] + sm[1][tid]) + (sm[2][tid] + sm[3][tid]);
    }
}

__global__ __launch_bounds__(64)
void dice_final_kernel(const float* __restrict__ partial,
                       float*       __restrict__ out) {
    const int b = blockIdx.x;
    const int t = threadIdx.x;     // one slab-column per lane (64 slabs)

    float acc[NPART];
#pragma unroll
    for (int k = 0; k < NPART; ++k)
        acc[k] = partial[(long)k * NBLK + b * SLABS + t];

#pragma unroll
    for (int k = 0; k < NPART; ++k)
        acc[k] = wave_reduce_dpp(acc[k]);   // totals valid in lane 63

    if (t == 63) {
        float s = 0.f;
#pragma unroll
        for (int c = 0; c < C_CLS; ++c) {
            const float is = acc[c * 3 + 0];
            const float o  = acc[c * 3 + 1];
            const float cn = acc[c * 3 + 2];
            s += (2.f * o + 1.f) / (is + cn + 1.f);
        }
        out[b] = -s * (1.f / (float)C_CLS);
    }
}

extern "C" void kernel_launch(void* const* d_in, const int* in_sizes, int n_in,
                              void* d_out, int out_size, void* d_ws, size_t ws_size,
                              hipStream_t stream) {
    const float* pred = (const float*)d_in[0];
    const int*   tgt  = (const int*)d_in[1];
    float*       out  = (float*)d_out;
    float*       partial = (float*)d_ws;   // 48 * 512 * 4 B = 98304 B

    dice_partial_kernel<<<NBLK, 256, 0, stream>>>(pred, tgt, partial);
    dice_final_kernel<<<BATCH, 64, 0, stream>>>(partial, out);
}

// Round 10
// 38.202 us; speedup vs baseline: 1.4955x; 1.4955x over previous
//
#include <hip/hip_runtime.h>

// SoftDiceLoss: predictions [B=8, C=16, H=512, W=512] fp32, targets [B,H,W] int32.
// out[b] = -(1/C) * sum_c (2*overlap[b,c] + 1) / (i_sum[b,c] + count[b,c] + 1)
//
// Stage 1: 512 blocks = (8 batches x 64 slabs of 4096 positions) x 256 thr.
//   Each thread owns 16 positions; targets packed 4 bits each into ONE u64
//   (tpack). The 16 pred class-segments stream sequentially (4 float4 per
//   class per thread); in-loop body is load+accumulate ONLY into
//   isum[16]/ov[16]/cnt[16] per-thread regs (statically indexed via full
//   unroll). ALL wave reductions (48 DPP chains, pure VALU) run once after
//   the loop -> LDS -> partial[comp][block].
//   __launch_bounds__(256, 2): grid is 2 blocks/CU anyway, so allow 256
//   VGPR -> no scratch spill (R9 failed here: 64 VGPR cap => 88 MB spill).
// Stage 2: 8 blocks x 64 threads: thread t reduces one slab-column,
//   lane 63 computes the 16 fracs and writes out[b].

constexpr int  C_CLS   = 16;
constexpr long HW      = 512L * 512L;   // 262144 positions per (b,c) plane
constexpr int  BATCH   = 8;
constexpr int  SLAB    = 4096;          // positions per block
constexpr int  SLABS   = (int)(HW / SLAB);   // 64 per batch
constexpr int  NBLK    = BATCH * SLABS;      // 512
constexpr int  NPART   = 3 * C_CLS;          // 48 components

// Full wave64 sum via DPP (rocPRIM pattern). Result valid in lane 63.
__device__ __forceinline__ float wave_reduce_dpp(float x) {
    int t;
    t = __builtin_amdgcn_update_dpp(0, __float_as_int(x), 0x111, 0xf, 0xf, true); // row_shr:1
    x += __int_as_float(t);
    t = __builtin_amdgcn_update_dpp(0, __float_as_int(x), 0x112, 0xf, 0xf, true); // row_shr:2
    x += __int_as_float(t);
    t = __builtin_amdgcn_update_dpp(0, __float_as_int(x), 0x114, 0xf, 0xf, true); // row_shr:4
    x += __int_as_float(t);
    t = __builtin_amdgcn_update_dpp(0, __float_as_int(x), 0x118, 0xf, 0xf, true); // row_shr:8
    x += __int_as_float(t);
    t = __builtin_amdgcn_update_dpp(0, __float_as_int(x), 0x142, 0xa, 0xf, true); // row_bcast:15
    x += __int_as_float(t);
    t = __builtin_amdgcn_update_dpp(0, __float_as_int(x), 0x143, 0xc, 0xf, true); // row_bcast:31
    x += __int_as_float(t);
    return x;
}

__global__ __launch_bounds__(256, 2)
void dice_partial_kernel(const float* __restrict__ pred,
                         const int*   __restrict__ tgt,
                         float*       __restrict__ partial) {
    const int g    = blockIdx.x;
    const int slab = g & (SLABS - 1);
    const int b    = g >> 6;
    const int tid  = threadIdx.x;
    const int lane = tid & 63;
    const int wv   = tid >> 6;

    const long sbase = (long)slab * SLAB;        // within plane
    const int* tb = tgt + (long)b * HW + sbase;

    // pack this thread's 16 target values into one u64 (4 bits each)
    unsigned long long tpack = 0ull;
#pragma unroll
    for (int j = 0; j < 4; ++j) {
        const int4 tv = *reinterpret_cast<const int4*>(tb + j * 1024 + tid * 4);
        const unsigned nib = (unsigned)tv.x | ((unsigned)tv.y << 4)
                           | ((unsigned)tv.z << 8) | ((unsigned)tv.w << 12);
        tpack |= (unsigned long long)nib << (16 * j);
    }

    const float* pb = pred + (long)b * C_CLS * HW + sbase + tid * 4;

    float isum[C_CLS], ov[C_CLS], cnt[C_CLS];

#pragma unroll
    for (int c = 0; c < C_CLS; ++c) {
        // exact per-nibble (t==c) mask: bit 4i of m = match at position i
        unsigned long long x = tpack ^ ((unsigned long long)c * 0x1111111111111111ull);
        x |= x >> 2;
        x |= x >> 1;
        const unsigned long long m = ~x & 0x1111111111111111ull;

        const float* cb = pb + (long)c * HW;
        const float4 p0 = *reinterpret_cast<const float4*>(cb + 0 * 1024);
        const float4 p1 = *reinterpret_cast<const float4*>(cb + 1 * 1024);
        const float4 p2 = *reinterpret_cast<const float4*>(cb + 2 * 1024);
        const float4 p3 = *reinterpret_cast<const float4*>(cb + 3 * 1024);

        float is = 0.f, o = 0.f;
        const unsigned mb0 = (unsigned)m;
        is += (p0.x + p0.y) + (p0.z + p0.w);
        o  += ((mb0 & 0x0001u) ? p0.x : 0.f) + ((mb0 & 0x0010u) ? p0.y : 0.f)
            + ((mb0 & 0x0100u) ? p0.z : 0.f) + ((mb0 & 0x1000u) ? p0.w : 0.f);
        const unsigned mb1 = (unsigned)(m >> 16);
        is += (p1.x + p1.y) + (p1.z + p1.w);
        o  += ((mb1 & 0x0001u) ? p1.x : 0.f) + ((mb1 & 0x0010u) ? p1.y : 0.f)
            + ((mb1 & 0x0100u) ? p1.z : 0.f) + ((mb1 & 0x1000u) ? p1.w : 0.f);
        const unsigned mb2 = (unsigned)(m >> 32);
        is += (p2.x + p2.y) + (p2.z + p2.w);
        o  += ((mb2 & 0x0001u) ? p2.x : 0.f) + ((mb2 & 0x0010u) ? p2.y : 0.f)
            + ((mb2 & 0x0100u) ? p2.z : 0.f) + ((mb2 & 0x1000u) ? p2.w : 0.f);
        const unsigned mb3 = (unsigned)(m >> 48);
        is += (p3.x + p3.y) + (p3.z + p3.w);
        o  += ((mb3 & 0x0001u) ? p3.x : 0.f) + ((mb3 & 0x0010u) ? p3.y : 0.f)
            + ((mb3 & 0x0100u) ? p3.z : 0.f) + ((mb3 & 0x1000u) ? p3.w : 0.f);

        isum[c] = is;
        ov[c]   = o;
        cnt[c]  = (float)__popcll(m);
    }

    // 48 independent DPP wave reductions (pipelined, pure VALU)
    __shared__ float sm[4][NPART];
#pragma unroll
    for (int c = 0; c < C_CLS; ++c) {
        const float is = wave_reduce_dpp(isum[c]);
        const float o  = wave_reduce_dpp(ov[c]);
        const float cn = wave_reduce_dpp(cnt[c]);
        if (lane == 63) {
            sm[wv][c * 3 + 0] = is;
            sm[wv][c * 3 + 1] = o;
            sm[wv][c * 3 + 2] = cn;
        }
    }

    __syncthreads();
    if (tid < NPART) {
        // component-major layout: partial[comp][block] for coalesced stage-2
        partial[(long)tid * NBLK + g] =
            (sm[0][tid] + sm[1][tid]) + (sm[2][tid] + sm[3][tid]);
    }
}

__global__ __launch_bounds__(64)
void dice_final_kernel(const float* __restrict__ partial,
                       float*       __restrict__ out) {
    const int b = blockIdx.x;
    const int t = threadIdx.x;     // one slab-column per lane (64 slabs)

    float acc[NPART];
#pragma unroll
    for (int k = 0; k < NPART; ++k)
        acc[k] = partial[(long)k * NBLK + b * SLABS + t];

#pragma unroll
    for (int k = 0; k < NPART; ++k)
        acc[k] = wave_reduce_dpp(acc[k]);   // totals valid in lane 63

    if (t == 63) {
        float s = 0.f;
#pragma unroll
        for (int c = 0; c < C_CLS; ++c) {
            const float is = acc[c * 3 + 0];
            const float o  = acc[c * 3 + 1];
            const float cn = acc[c * 3 + 2];
            s += (2.f * o + 1.f) / (is + cn + 1.f);
        }
        out[b] = -s * (1.f / (float)C_CLS);
    }
}

extern "C" void kernel_launch(void* const* d_in, const int* in_sizes, int n_in,
                              void* d_out, int out_size, void* d_ws, size_t ws_size,
                              hipStream_t stream) {
    const float* pred = (const float*)d_in[0];
    const int*   tgt  = (const int*)d_in[1];
    float*       out  = (float*)d_out;
    float*       partial = (float*)d_ws;   // 48 * 512 * 4 B = 98304 B

    dice_partial_kernel<<<NBLK, 256, 0, stream>>>(pred, tgt, partial);
    dice_final_kernel<<<BATCH, 64, 0, stream>>>(partial, out);
}